// Round 12
// baseline (257.346 us; speedup 1.0000x reference)
//
#include <hip/hip_runtime.h>

#define N_NODES 100000
#define N_EDGES 1600000
#define BSHIFT 7
#define NBUCK 782     // ceil(N_NODES/128)
#define NB2 (2 * NBUCK)
#define NCHUNK 500
#define CH 3200       // N_EDGES / NCHUNK exactly
#define G1BLK 1563    // ceil(N_NODES/64) gemm1 tiles

typedef __attribute__((ext_vector_type(8))) short bf16x8;
typedef __attribute__((ext_vector_type(4))) float f32x4;

// bf16 helpers (RTNE pack; unpack = shift to high half)
__device__ __forceinline__ unsigned pack_bf16x2(float a, float b) {
  unsigned ua = __float_as_uint(a);
  unsigned ub = __float_as_uint(b);
  ua = ua + 0x7fffu + ((ua >> 16) & 1u);
  ub = ub + 0x7fffu + ((ub >> 16) & 1u);
  return (ua >> 16) | (ub & 0xffff0000u);
}
__device__ __forceinline__ unsigned short bf16u(float f) {
  unsigned u = __float_as_uint(f);
  u = u + 0x7fffu + ((u >> 16) & 1u);
  return (unsigned short)(u >> 16);
}
__device__ __forceinline__ float bf_lo(unsigned u) { return __uint_as_float(u << 16); }
__device__ __forceinline__ float bf_hi(unsigned u) { return __uint_as_float(u & 0xffff0000u); }

#define LPAD 136

// ---- k_histg1: heterogeneous launch: chunk histograms (blocks 0..NCHUNK) ------------------
// PLUS oi-free GEMM1 tiles (blocks NCHUNK..NCHUNK+G1BLK). gemm1 no longer needs the
// partition pipeline (oi deferred to agg1's gather) -> overlaps hist's idle bandwidth.

__global__ __launch_bounds__(256) void k_histg1(const int* __restrict__ src,
                                                const int* __restrict__ dst,
                                                unsigned* __restrict__ histGd,
                                                unsigned* __restrict__ histGs,
                                                const float* __restrict__ x,
                                                const float* __restrict__ W1,
                                                unsigned short* __restrict__ h1b) {
  __shared__ __align__(16) char smem[52224];  // union: hist 6.3KB | gemm1 Xs+Ws 52.2KB
  const int t = threadIdx.x, jb = blockIdx.x;
  if (jb < NCHUNK) {
    unsigned* hd = (unsigned*)smem;
    unsigned* hs = hd + NBUCK;
    for (int i = t; i < NBUCK; i += 256) { hd[i] = 0u; hs[i] = 0u; }
    __syncthreads();
    const int e0 = jb * CH;
    for (int e = e0 + t; e < e0 + CH; e += 256) {
      atomicAdd(&hd[(unsigned)dst[e] >> BSHIFT], 1u);
      atomicAdd(&hs[(unsigned)src[e] >> BSHIFT], 1u);
    }
    __syncthreads();
    for (int i = t; i < NBUCK; i += 256) {
      histGd[(size_t)i * NCHUNK + jb] = hd[i];
      histGs[(size_t)i * NCHUNK + jb] = hs[i];
    }
  } else {
    unsigned short* Xs = (unsigned short*)smem;            // 64*LPAD
    unsigned short* Ws = (unsigned short*)smem + 64 * LPAD; // 128*LPAD
    const int row0 = (jb - NCHUNK) * 64;
    // W1 f32 [k][n] -> Ws[n][k] bf16 (self-transpose; W1 is L2-hot across blocks)
    for (int j = 0; j < 32; ++j) {
      int idx = t + 256 * j;        // 8192 float2s
      int k = idx >> 6;
      int n2 = (idx & 63) * 2;
      float2 w = *(const float2*)(W1 + (size_t)k * 128 + n2);
      Ws[n2 * LPAD + k] = bf16u(w.x);
      Ws[(n2 + 1) * LPAD + k] = bf16u(w.y);
    }
#pragma unroll
    for (int j = 0; j < 4; ++j) {
      int q = t + 256 * j;
      int r = q >> 4, c = q & 15;
      int gr = row0 + r; if (gr >= N_NODES) gr = N_NODES - 1;
      const float* xp = x + (size_t)gr * 128 + c * 8;
      float4 v0 = *(const float4*)(xp);
      float4 v1 = *(const float4*)(xp + 4);
      uint4 pk;
      pk.x = pack_bf16x2(v0.x, v0.y);
      pk.y = pack_bf16x2(v0.z, v0.w);
      pk.z = pack_bf16x2(v1.x, v1.y);
      pk.w = pack_bf16x2(v1.z, v1.w);
      *(uint4*)(Xs + r * LPAD + c * 8) = pk;
    }
    __syncthreads();
    const int w = t >> 6, lane = t & 63;
    const int m = lane & 15;
    const int q8 = (lane >> 4) * 8;
    f32x4 acc[8];
#pragma unroll
    for (int i = 0; i < 8; ++i) acc[i] = (f32x4){0.f, 0.f, 0.f, 0.f};
    const unsigned short* xrow = Xs + (w * 16 + m) * LPAD;
#pragma unroll
    for (int ks = 0; ks < 4; ++ks) {
      bf16x8 a = *(const bf16x8*)(xrow + ks * 32 + q8);
#pragma unroll
      for (int ct = 0; ct < 8; ++ct) {
        bf16x8 b = *(const bf16x8*)(Ws + (ct * 16 + m) * LPAD + ks * 32 + q8);
        acc[ct] = __builtin_amdgcn_mfma_f32_16x16x32_bf16(a, b, acc[ct], 0, 0, 0);
      }
    }
    const int rbase = row0 + w * 16 + (lane >> 4) * 4;
#pragma unroll
    for (int ct = 0; ct < 8; ++ct) {
      int coln = ct * 16 + m;
#pragma unroll
      for (int r = 0; r < 4; ++r) {
        int grow = rbase + r;
        if (grow < N_NODES) h1b[(size_t)grow * 128 + coln] = bf16u(acc[ct][r]);
      }
    }
  }
}

// block per (bucket, stream): exclusive scan of NCHUNK chunk-counts in place + total.
__global__ __launch_bounds__(256) void k_offs(unsigned* __restrict__ histGd,
                                              unsigned* __restrict__ histGs,
                                              unsigned* __restrict__ btot) {
  __shared__ unsigned sd[256];
  const int bu = blockIdx.x, t = threadIdx.x;
  unsigned* col = (bu < NBUCK) ? histGd + (size_t)bu * NCHUNK
                               : histGs + (size_t)(bu - NBUCK) * NCHUNK;
  unsigned v[2], s = 0;
#pragma unroll
  for (int i = 0; i < 2; ++i) {
    int idx = t * 2 + i;
    v[i] = (idx < NCHUNK) ? col[idx] : 0u;
    s += v[i];
  }
  sd[t] = s;
  __syncthreads();
  for (int d = 1; d < 256; d <<= 1) {
    unsigned a = (t >= d) ? sd[t - d] : 0u;
    __syncthreads();
    sd[t] += a;
    __syncthreads();
  }
  unsigned run = sd[t] - s;
#pragma unroll
  for (int i = 0; i < 2; ++i) {
    int idx = t * 2 + i;
    if (idx < NCHUNK) { unsigned tv = v[i]; col[idx] = run; run += tv; }
  }
  if (t == 255) btot[bu] = run;
}

// two blocks: scan dst totals -> bbase, src totals -> sbase. Also preps Wt2 (idle threads).
__global__ __launch_bounds__(1024) void k_bscan2(const unsigned* __restrict__ btot,
                                                 int* __restrict__ bbase,
                                                 int* __restrict__ sbase,
                                                 int* __restrict__ row_ptr,
                                                 const float* __restrict__ W2,
                                                 unsigned short* __restrict__ Wt2) {
  __shared__ unsigned sd[1024];
  const int t = threadIdx.x;
  for (int e = blockIdx.x * 1024 + t; e < 48 * 128; e += 2048) {
    int n = e >> 7, k = e & 127;
    float v = (n < 40) ? W2[k * 40 + n] : 0.f;
    Wt2[n * 128 + k] = bf16u(v);
  }
  const unsigned* bt = btot + (blockIdx.x ? NBUCK : 0);
  int* ob = blockIdx.x ? sbase : bbase;
  unsigned v = (t < NBUCK) ? bt[t] : 0u;
  sd[t] = v;
  __syncthreads();
  for (int d = 1; d < 1024; d <<= 1) {
    unsigned a = (t >= d) ? sd[t - d] : 0u;
    __syncthreads();
    sd[t] += a;
    __syncthreads();
  }
  if (t < NBUCK) ob[t] = (int)(sd[t] - v);
  if (t == 0) {
    ob[NBUCK] = N_EDGES;
    if (blockIdx.x == 0) row_ptr[N_NODES] = N_EDGES;
  }
}

// ---- k_part: LDS counting sort per chunk, both streams, ONE combined scan (R11) ---------

__global__ __launch_bounds__(256) void k_part(const int* __restrict__ src,
                                              const int* __restrict__ dst,
                                              const unsigned* __restrict__ histGd,
                                              const unsigned* __restrict__ histGs,
                                              const int* __restrict__ bbase,
                                              const int* __restrict__ sbase,
                                              int* __restrict__ ebuf,
                                              unsigned char* __restrict__ ebuf2) {
  __shared__ int pk_s[CH];
  __shared__ unsigned short bkD[CH];
  __shared__ int srt[CH];
  __shared__ unsigned short bkO[CH];
  __shared__ unsigned cnt[NB2];
  __shared__ int gb[NB2];
  __shared__ unsigned pscan[256];
  const int t = threadIdx.x, j = blockIdx.x;
  const int e0 = j * CH;
  for (int i = t; i < NB2; i += 256) cnt[i] = 0u;
  __syncthreads();
  for (int i = t; i < CH; i += 256) {
    int d = dst[e0 + i], s = src[e0 + i];
    pk_s[i] = ((d & 127) << 17) | s;
    int bd = (unsigned)d >> BSHIFT;
    bkD[i] = (unsigned short)bd;
    atomicAdd(&cnt[bd], 1u);
    atomicAdd(&cnt[NBUCK + ((unsigned)s >> BSHIFT)], 1u);
  }
  __syncthreads();
  unsigned loc[7], ssum = 0;
#pragma unroll
  for (int k = 0; k < 7; ++k) {
    int idx = t * 7 + k;
    loc[k] = (idx < NB2) ? cnt[idx] : 0u;
    ssum += loc[k];
  }
  pscan[t] = ssum;
  __syncthreads();
  for (int d2 = 1; d2 < 256; d2 <<= 1) {
    unsigned a = (t >= d2) ? pscan[t - d2] : 0u;
    __syncthreads();
    pscan[t] += a;
    __syncthreads();
  }
  unsigned run = pscan[t] - ssum;
#pragma unroll
  for (int k = 0; k < 7; ++k) {
    int idx = t * 7 + k;
    if (idx < NBUCK) {
      cnt[idx] = run;
      gb[idx] = bbase[idx] + (int)histGd[(size_t)idx * NCHUNK + j] - (int)run;
    } else if (idx < NB2) {
      unsigned runS = run - CH;
      cnt[idx] = runS;
      int b = idx - NBUCK;
      gb[idx] = sbase[b] + (int)histGs[(size_t)b * NCHUNK + j] - (int)runS;
    }
    run += loc[k];
  }
  __syncthreads();
  for (int i = t; i < CH; i += 256) {
    int b = bkD[i];
    unsigned pos = atomicAdd(&cnt[b], 1u);
    srt[pos] = pk_s[i];
    bkO[pos] = (unsigned short)b;
  }
  __syncthreads();
  for (int i = t; i < CH; i += 256)
    ebuf[gb[bkO[i]] + i] = srt[i];
  __syncthreads();
  unsigned char* srtB = (unsigned char*)srt;
  for (int i = t; i < CH; i += 256) {
    int s = pk_s[i] & 0x1FFFF;
    int b2 = NBUCK + ((unsigned)s >> BSHIFT);
    unsigned pos = atomicAdd(&cnt[b2], 1u);
    srtB[pos] = (unsigned char)(s & 127);
    bkO[pos] = (unsigned short)b2;
  }
  __syncthreads();
  for (int i = t; i < CH; i += 256)
    ebuf2[gb[bkO[i]] + i] = srtB[i];
}

// Fused per-bucket pass (R11): degrees -> oi/ii/coi, row_ptr, clustered csr fill.
__global__ __launch_bounds__(256) void k_buckets(const int* __restrict__ ebuf,
                                                 const unsigned char* __restrict__ ebuf2,
                                                 const int* __restrict__ bbase,
                                                 const int* __restrict__ sbase,
                                                 float* __restrict__ oi,
                                                 int* __restrict__ row_ptr,
                                                 int* __restrict__ csr_src,
                                                 float* __restrict__ ii,
                                                 float* __restrict__ coi) {
  __shared__ unsigned cntS[128];
  __shared__ unsigned cntD[128];
  __shared__ unsigned sc2[128];
  __shared__ int eL[3072];
  const int b = blockIdx.x, t = threadIdx.x;
  const int node0 = b << BSHIFT;
  if (t < 128) { cntS[t] = 0u; cntD[t] = 0u; }
  __syncthreads();
  const int sbeg = sbase[b], send = sbase[b + 1];
  for (int j = sbeg + t; j < send; j += 256)
    atomicAdd(&cntS[ebuf2[j]], 1u);
  const int base = bbase[b], end = bbase[b + 1];
  const int cnt = end - base;
  const bool fit = (cnt <= 3072);
  for (int j = t; j < cnt; j += 256) {
    int pk = ebuf[base + j];
    if (fit) eL[j] = pk;
    atomicAdd(&cntD[(unsigned)pk >> 17], 1u);
  }
  __syncthreads();
  unsigned cD = (t < 128) ? cntD[t] : 0u;
  if (t < 128) sc2[t] = cD;
  __syncthreads();
  for (int d = 1; d < 128; d <<= 1) {
    unsigned a = (t < 128 && t >= d) ? sc2[t - d] : 0u;
    __syncthreads();
    if (t < 128) sc2[t] += a;
    __syncthreads();
  }
  if (t < 128) {
    unsigned ex = sc2[t] - cD;
    unsigned cs = cntS[t]; if (cs < 1u) cs = 1u;
    float o = rsqrtf((float)cs);
    int n = node0 + t;
    if (n < N_NODES) {
      oi[n] = o;
      row_ptr[n] = base + (int)ex;
      unsigned c = cD; if (c < 1u) c = 1u;
      float iv = rsqrtf((float)c);
      ii[n] = iv;
      coi[n] = iv * o;
    }
    cntD[t] = ex;
  }
  __syncthreads();
  for (int j = t; j < cnt; j += 256) {
    int pk = fit ? eL[j] : ebuf[base + j];
    unsigned dn = (unsigned)pk >> 17;
    unsigned slot = atomicAdd(&cntD[dn], 1u);
    csr_src[base + (int)slot] = pk & 0x1FFFF;
  }
}

// ---- AGG1+GEMM2 fused: h2b = bf16( (coi_d * relu(sum oi_s * h1raw[s])) @ W2 ) -----------
// oi applied per gathered row (FMA); oi table 400KB L2-hot, 16-lane broadcast loads.

__global__ __launch_bounds__(256) void k_agg1g2(const unsigned short* __restrict__ h1b,
                                                const int* __restrict__ csr_src,
                                                const int* __restrict__ row_ptr,
                                                const float* __restrict__ oi,
                                                const float* __restrict__ coi,
                                                const unsigned short* __restrict__ Wt2,
                                                unsigned short* __restrict__ h2b) {
  __shared__ unsigned short Gs[16 * LPAD];
  __shared__ unsigned short Ws[48 * LPAD];
  const int t = threadIdx.x;
  const int node0 = blockIdx.x * 16;
#pragma unroll
  for (int j = 0; j < 3; ++j) {
    int q = t + 256 * j;
    int n = q >> 4, cc = q & 15;
    *(uint4*)(Ws + n * LPAD + cc * 8) = *(const uint4*)(Wt2 + n * 128 + cc * 8);
  }
  const int node = node0 + (t >> 4);
  const int c = t & 15;
  const int beg = row_ptr[node];
  const int end = row_ptr[node + 1];
  float4 a0 = make_float4(0.f, 0.f, 0.f, 0.f);
  float4 a1 = make_float4(0.f, 0.f, 0.f, 0.f);
  int j = beg;
  for (; j + 8 <= end; j += 8) {
    uint4 v[8]; float os[8];
#pragma unroll
    for (int i = 0; i < 8; ++i) {
      int s = csr_src[j + i];
      v[i] = *(const uint4*)(h1b + (size_t)s * 128 + 8 * c);
      os[i] = oi[s];
    }
#pragma unroll
    for (int i = 0; i < 8; ++i) {
      a0.x += bf_lo(v[i].x) * os[i]; a0.y += bf_hi(v[i].x) * os[i];
      a0.z += bf_lo(v[i].y) * os[i]; a0.w += bf_hi(v[i].y) * os[i];
      a1.x += bf_lo(v[i].z) * os[i]; a1.y += bf_hi(v[i].z) * os[i];
      a1.z += bf_lo(v[i].w) * os[i]; a1.w += bf_hi(v[i].w) * os[i];
    }
  }
  if (j + 4 <= end) {
    uint4 v[4]; float os[4];
#pragma unroll
    for (int i = 0; i < 4; ++i) {
      int s = csr_src[j + i];
      v[i] = *(const uint4*)(h1b + (size_t)s * 128 + 8 * c);
      os[i] = oi[s];
    }
#pragma unroll
    for (int i = 0; i < 4; ++i) {
      a0.x += bf_lo(v[i].x) * os[i]; a0.y += bf_hi(v[i].x) * os[i];
      a0.z += bf_lo(v[i].y) * os[i]; a0.w += bf_hi(v[i].y) * os[i];
      a1.x += bf_lo(v[i].z) * os[i]; a1.y += bf_hi(v[i].z) * os[i];
      a1.z += bf_lo(v[i].w) * os[i]; a1.w += bf_hi(v[i].w) * os[i];
    }
    j += 4;
  }
  for (; j < end; ++j) {
    int s = csr_src[j];
    uint4 v = *(const uint4*)(h1b + (size_t)s * 128 + 8 * c);
    float os1 = oi[s];
    a0.x += bf_lo(v.x) * os1; a0.y += bf_hi(v.x) * os1;
    a0.z += bf_lo(v.y) * os1; a0.w += bf_hi(v.y) * os1;
    a1.x += bf_lo(v.z) * os1; a1.y += bf_hi(v.z) * os1;
    a1.z += bf_lo(v.w) * os1; a1.w += bf_hi(v.w) * os1;
  }
  float sc = coi[node];
  uint4 pk;
  pk.x = pack_bf16x2(fmaxf(a0.x, 0.f) * sc, fmaxf(a0.y, 0.f) * sc);
  pk.y = pack_bf16x2(fmaxf(a0.z, 0.f) * sc, fmaxf(a0.w, 0.f) * sc);
  pk.z = pack_bf16x2(fmaxf(a1.x, 0.f) * sc, fmaxf(a1.y, 0.f) * sc);
  pk.w = pack_bf16x2(fmaxf(a1.z, 0.f) * sc, fmaxf(a1.w, 0.f) * sc);
  *(uint4*)(Gs + (t >> 4) * LPAD + 8 * c) = pk;
  __syncthreads();
  const int w = t >> 6, lane = t & 63;
  if (w < 3) {
    const int m = lane & 15;
    const int q8 = (lane >> 4) * 8;
    f32x4 acc = (f32x4){0.f, 0.f, 0.f, 0.f};
    const unsigned short* grow_p = Gs + m * LPAD;
#pragma unroll
    for (int ks = 0; ks < 4; ++ks) {
      bf16x8 a = *(const bf16x8*)(grow_p + ks * 32 + q8);
      bf16x8 b = *(const bf16x8*)(Ws + (w * 16 + m) * LPAD + ks * 32 + q8);
      acc = __builtin_amdgcn_mfma_f32_16x16x32_bf16(a, b, acc, 0, 0, 0);
    }
    int coln = w * 16 + m;
    if (coln < 40) {
      const int rbase = (lane >> 4) * 4;
#pragma unroll
      for (int r = 0; r < 4; ++r)
        h2b[(size_t)(node0 + rbase + r) * 64 + coln] = bf16u(acc[r]);
    }
  }
}

// ---------------- AGG2: out = ii * sum h2[src]  (8 lanes/node, uint4; lanes 0-4 active) ----

__global__ __launch_bounds__(256) void k_agg2(const unsigned short* __restrict__ h2b,
                                              const int* __restrict__ csr_src,
                                              const int* __restrict__ row_ptr,
                                              const float* __restrict__ ii,
                                              float* __restrict__ out) {
  const int t = threadIdx.x;
  const int node = blockIdx.x * 32 + (t >> 3);
  const int c = t & 7;
  if (c >= 5) return;  // 40 ch = 5 lanes x 8 ch
  const int beg = row_ptr[node];
  const int end = row_ptr[node + 1];
  float a0 = 0.f, a1 = 0.f, a2 = 0.f, a3 = 0.f, a4 = 0.f, a5 = 0.f, a6 = 0.f, a7 = 0.f;
  int j = beg;
  for (; j + 8 <= end; j += 8) {
    uint4 v[8];
#pragma unroll
    for (int i = 0; i < 8; ++i) {
      int s = csr_src[j + i];
      v[i] = *(const uint4*)(h2b + (size_t)s * 64 + 8 * c);
    }
#pragma unroll
    for (int i = 0; i < 8; ++i) {
      a0 += bf_lo(v[i].x); a1 += bf_hi(v[i].x);
      a2 += bf_lo(v[i].y); a3 += bf_hi(v[i].y);
      a4 += bf_lo(v[i].z); a5 += bf_hi(v[i].z);
      a6 += bf_lo(v[i].w); a7 += bf_hi(v[i].w);
    }
  }
  if (j + 4 <= end) {
    uint4 v[4];
#pragma unroll
    for (int i = 0; i < 4; ++i) {
      int s = csr_src[j + i];
      v[i] = *(const uint4*)(h2b + (size_t)s * 64 + 8 * c);
    }
#pragma unroll
    for (int i = 0; i < 4; ++i) {
      a0 += bf_lo(v[i].x); a1 += bf_hi(v[i].x);
      a2 += bf_lo(v[i].y); a3 += bf_hi(v[i].y);
      a4 += bf_lo(v[i].z); a5 += bf_hi(v[i].z);
      a6 += bf_lo(v[i].w); a7 += bf_hi(v[i].w);
    }
    j += 4;
  }
  for (; j < end; ++j) {
    int s = csr_src[j];
    uint4 v = *(const uint4*)(h2b + (size_t)s * 64 + 8 * c);
    a0 += bf_lo(v.x); a1 += bf_hi(v.x);
    a2 += bf_lo(v.y); a3 += bf_hi(v.y);
    a4 += bf_lo(v.z); a5 += bf_hi(v.z);
    a6 += bf_lo(v.w); a7 += bf_hi(v.w);
  }
  float sc = ii[node];
  float4 o0 = make_float4(a0 * sc, a1 * sc, a2 * sc, a3 * sc);
  float4 o1 = make_float4(a4 * sc, a5 * sc, a6 * sc, a7 * sc);
  float* op = out + (size_t)node * 40 + 8 * c;
  *(float4*)(op) = o0;
  *(float4*)(op + 4) = o1;
}

// ---------------- launch ----------------

extern "C" void kernel_launch(void* const* d_in, const int* in_sizes, int n_in,
                              void* d_out, int out_size, void* d_ws, size_t ws_size,
                              hipStream_t stream) {
  const float* x  = (const float*)d_in[0];
  const int* ei   = (const int*)d_in[1];
  const float* W1 = (const float*)d_in[2];
  const float* W2 = (const float*)d_in[3];
  const int* src = ei;
  const int* dst = ei + N_EDGES;
  float* out = (float*)d_out;

  char* p = (char*)d_ws;
  auto alloc = [&](size_t b) -> void* {
    char* r = p;
    p += (b + 255) & ~(size_t)255;
    return (void*)r;
  };
  float* oi             = (float*)alloc((size_t)N_NODES * 4);
  float* ii             = (float*)alloc((size_t)N_NODES * 4);
  float* coi            = (float*)alloc((size_t)N_NODES * 4);
  int* row_ptr          = (int*)alloc((size_t)(N_NODES + 1) * 4);
  unsigned* histGd      = (unsigned*)alloc((size_t)NBUCK * NCHUNK * 4);
  unsigned* histGs      = (unsigned*)alloc((size_t)NBUCK * NCHUNK * 4);
  unsigned* btot        = (unsigned*)alloc((size_t)2 * NBUCK * 4);
  int* bbase            = (int*)alloc((size_t)(NBUCK + 1) * 4);
  int* sbase            = (int*)alloc((size_t)(NBUCK + 1) * 4);
  int* ebuf             = (int*)alloc((size_t)N_EDGES * 4);
  unsigned char* ebuf2  = (unsigned char*)alloc((size_t)N_EDGES);
  int* csr_src          = (int*)alloc((size_t)N_EDGES * 4);
  unsigned short* Wt2   = (unsigned short*)alloc((size_t)48 * 128 * 2);
  unsigned short* h1b   = (unsigned short*)alloc((size_t)N_NODES * 128 * 2);
  unsigned short* h2b   = (unsigned short*)alloc((size_t)N_NODES * 64 * 2);

  k_histg1<<<NCHUNK + G1BLK, 256, 0, stream>>>(src, dst, histGd, histGs, x, W1, h1b);
  k_offs<<<2 * NBUCK, 256, 0, stream>>>(histGd, histGs, btot);
  k_bscan2<<<2, 1024, 0, stream>>>(btot, bbase, sbase, row_ptr, W2, Wt2);
  k_part<<<NCHUNK, 256, 0, stream>>>(src, dst, histGd, histGs, bbase, sbase, ebuf, ebuf2);
  k_buckets<<<NBUCK, 256, 0, stream>>>(ebuf, ebuf2, bbase, sbase, oi, row_ptr, csr_src,
                                       ii, coi);
  k_agg1g2<<<N_NODES / 16, 256, 0, stream>>>(h1b, csr_src, row_ptr, oi, coi, Wt2, h2b);
  k_agg2<<<N_NODES / 32, 256, 0, stream>>>(h2b, csr_src, row_ptr, ii, out);
}

// Round 13
// 249.671 us; speedup vs baseline: 1.0307x; 1.0307x over previous
//
#include <hip/hip_runtime.h>

#define N_NODES 100000
#define N_EDGES 1600000
#define BSHIFT 7
#define NBUCK 782     // ceil(N_NODES/128)
#define NB2 (2 * NBUCK)
#define NCHUNK 500
#define CH 3200       // N_EDGES / NCHUNK exactly
#define NBG 49        // ceil(NBUCK/16) bucket-groups for k_offs

typedef __attribute__((ext_vector_type(8))) short bf16x8;
typedef __attribute__((ext_vector_type(4))) float f32x4;

// bf16 helpers (RTNE pack; unpack = shift to high half)
__device__ __forceinline__ unsigned pack_bf16x2(float a, float b) {
  unsigned ua = __float_as_uint(a);
  unsigned ub = __float_as_uint(b);
  ua = ua + 0x7fffu + ((ua >> 16) & 1u);
  ub = ub + 0x7fffu + ((ub >> 16) & 1u);
  return (ua >> 16) | (ub & 0xffff0000u);
}
__device__ __forceinline__ unsigned short bf16u(float f) {
  unsigned u = __float_as_uint(f);
  u = u + 0x7fffu + ((u >> 16) & 1u);
  return (unsigned short)(u >> 16);
}
__device__ __forceinline__ float bf_lo(unsigned u) { return __uint_as_float(u << 16); }
__device__ __forceinline__ float bf_hi(unsigned u) { return __uint_as_float(u & 0xffff0000u); }

// ---- k_hist: per-chunk histograms -> histG_T[chunk][bucket] (contiguous writes) ---------
// + fused one-time weight prep (blocks 0..63).

__global__ __launch_bounds__(256) void k_hist(const int* __restrict__ src,
                                              const int* __restrict__ dst,
                                              unsigned* __restrict__ histGdT,
                                              unsigned* __restrict__ histGsT,
                                              const float* __restrict__ W1,
                                              const float* __restrict__ W2,
                                              unsigned short* __restrict__ Wt1,
                                              unsigned short* __restrict__ Wt2) {
  __shared__ unsigned hd[NBUCK];
  __shared__ unsigned hs[NBUCK];
  const int t = threadIdx.x, j = blockIdx.x;
  if (j < 64) {  // fused weight prep (once)
    int q = j * 256 + t;
    {
      int n = q >> 7, k = q & 127;
      Wt1[n * 128 + k] = bf16u(W1[k * 128 + n]);
    }
    if (q < 48 * 128) {
      int n = q >> 7, k = q & 127;
      float v = (n < 40) ? W2[k * 40 + n] : 0.f;
      Wt2[n * 128 + k] = bf16u(v);
    }
  }
  for (int i = t; i < NBUCK; i += 256) { hd[i] = 0u; hs[i] = 0u; }
  __syncthreads();
  const int e0 = j * CH;
  for (int e = e0 + t; e < e0 + CH; e += 256) {
    atomicAdd(&hd[(unsigned)dst[e] >> BSHIFT], 1u);
    atomicAdd(&hs[(unsigned)src[e] >> BSHIFT], 1u);
  }
  __syncthreads();
  for (int i = t; i < NBUCK; i += 256) {
    histGdT[(size_t)j * NBUCK + i] = hd[i];
    histGsT[(size_t)j * NBUCK + i] = hs[i];
  }
}

// ---- k_offs: 16 buckets/block, coalesced reads of histG_T; in-place exclusive scan ------
// Thread (js=t>>4, bl=t&15): bucket b0+bl, chunk slice [js*32, js*32+32).

__global__ __launch_bounds__(256) void k_offs(unsigned* __restrict__ histGdT,
                                              unsigned* __restrict__ histGsT,
                                              unsigned* __restrict__ btot) {
  __shared__ unsigned part[16][17];
  __shared__ unsigned base[16][17];
  const int g = blockIdx.x;
  unsigned* H = (g < NBG) ? histGdT : histGsT;
  unsigned* bt = btot + ((g < NBG) ? 0 : NBUCK);
  const int b0 = ((g < NBG) ? g : g - NBG) * 16;
  const int t = threadIdx.x;
  const int js = t >> 4, bl = t & 15;
  const int b = b0 + bl;
  const int j0 = js * 32;
  const int j1 = (j0 + 32 < NCHUNK) ? j0 + 32 : NCHUNK;
  unsigned s = 0;
  if (b < NBUCK)
    for (int j = j0; j < j1; ++j) s += H[(size_t)j * NBUCK + b];
  part[js][bl] = s;
  __syncthreads();
  if (js == 0) {
    unsigned run = 0;
#pragma unroll
    for (int k = 0; k < 16; ++k) { base[k][bl] = run; run += part[k][bl]; }
    if (b < NBUCK) bt[b] = run;
  }
  __syncthreads();
  if (b < NBUCK) {
    unsigned run = base[js][bl];
    for (int j = j0; j < j1; ++j) {
      unsigned v = H[(size_t)j * NBUCK + b];
      H[(size_t)j * NBUCK + b] = run;
      run += v;
    }
  }
}

// two blocks: scan dst totals -> bbase, src totals -> sbase.
__global__ __launch_bounds__(1024) void k_bscan2(const unsigned* __restrict__ btot,
                                                 int* __restrict__ bbase,
                                                 int* __restrict__ sbase,
                                                 int* __restrict__ row_ptr) {
  __shared__ unsigned sd[1024];
  const int t = threadIdx.x;
  const unsigned* bt = btot + (blockIdx.x ? NBUCK : 0);
  int* ob = blockIdx.x ? sbase : bbase;
  unsigned v = (t < NBUCK) ? bt[t] : 0u;
  sd[t] = v;
  __syncthreads();
  for (int d = 1; d < 1024; d <<= 1) {
    unsigned a = (t >= d) ? sd[t - d] : 0u;
    __syncthreads();
    sd[t] += a;
    __syncthreads();
  }
  if (t < NBUCK) ob[t] = (int)(sd[t] - v);
  if (t == 0) {
    ob[NBUCK] = N_EDGES;
    if (blockIdx.x == 0) row_ptr[N_NODES] = N_EDGES;
  }
}

// ---- k_part: LDS counting sort per chunk, both streams, ONE combined scan (R11) ---------
// histG_T base-read now one contiguous 6.3KB stream per block.

__global__ __launch_bounds__(256) void k_part(const int* __restrict__ src,
                                              const int* __restrict__ dst,
                                              const unsigned* __restrict__ histGdT,
                                              const unsigned* __restrict__ histGsT,
                                              const int* __restrict__ bbase,
                                              const int* __restrict__ sbase,
                                              int* __restrict__ ebuf,
                                              unsigned char* __restrict__ ebuf2) {
  __shared__ int pk_s[CH];
  __shared__ unsigned short bkD[CH];
  __shared__ int srt[CH];
  __shared__ unsigned short bkO[CH];
  __shared__ unsigned cnt[NB2];
  __shared__ int gb[NB2];
  __shared__ unsigned pscan[256];
  const int t = threadIdx.x, j = blockIdx.x;
  const int e0 = j * CH;
  for (int i = t; i < NB2; i += 256) cnt[i] = 0u;
  __syncthreads();
  for (int i = t; i < CH; i += 256) {
    int d = dst[e0 + i], s = src[e0 + i];
    pk_s[i] = ((d & 127) << 17) | s;
    int bd = (unsigned)d >> BSHIFT;
    bkD[i] = (unsigned short)bd;
    atomicAdd(&cnt[bd], 1u);
    atomicAdd(&cnt[NBUCK + ((unsigned)s >> BSHIFT)], 1u);
  }
  __syncthreads();
  unsigned loc[7], ssum = 0;
#pragma unroll
  for (int k = 0; k < 7; ++k) {
    int idx = t * 7 + k;
    loc[k] = (idx < NB2) ? cnt[idx] : 0u;
    ssum += loc[k];
  }
  pscan[t] = ssum;
  __syncthreads();
  for (int d2 = 1; d2 < 256; d2 <<= 1) {
    unsigned a = (t >= d2) ? pscan[t - d2] : 0u;
    __syncthreads();
    pscan[t] += a;
    __syncthreads();
  }
  unsigned run = pscan[t] - ssum;
#pragma unroll
  for (int k = 0; k < 7; ++k) {
    int idx = t * 7 + k;
    if (idx < NBUCK) {
      cnt[idx] = run;
      gb[idx] = bbase[idx] + (int)histGdT[(size_t)j * NBUCK + idx] - (int)run;
    } else if (idx < NB2) {
      unsigned runS = run - CH;
      cnt[idx] = runS;
      int b = idx - NBUCK;
      gb[idx] = sbase[b] + (int)histGsT[(size_t)j * NBUCK + b] - (int)runS;
    }
    run += loc[k];
  }
  __syncthreads();
  for (int i = t; i < CH; i += 256) {
    int b = bkD[i];
    unsigned pos = atomicAdd(&cnt[b], 1u);
    srt[pos] = pk_s[i];
    bkO[pos] = (unsigned short)b;
  }
  __syncthreads();
  for (int i = t; i < CH; i += 256)
    ebuf[gb[bkO[i]] + i] = srt[i];
  __syncthreads();
  unsigned char* srtB = (unsigned char*)srt;
  for (int i = t; i < CH; i += 256) {
    int s = pk_s[i] & 0x1FFFF;
    int b2 = NBUCK + ((unsigned)s >> BSHIFT);
    unsigned pos = atomicAdd(&cnt[b2], 1u);
    srtB[pos] = (unsigned char)(s & 127);
    bkO[pos] = (unsigned short)b2;
  }
  __syncthreads();
  for (int i = t; i < CH; i += 256)
    ebuf2[gb[bkO[i]] + i] = srtB[i];
}

// Fused per-bucket pass (R11): degrees -> oi/ii/coi, row_ptr, clustered csr fill.
__global__ __launch_bounds__(256) void k_buckets(const int* __restrict__ ebuf,
                                                 const unsigned char* __restrict__ ebuf2,
                                                 const int* __restrict__ bbase,
                                                 const int* __restrict__ sbase,
                                                 float* __restrict__ oi,
                                                 int* __restrict__ row_ptr,
                                                 int* __restrict__ csr_src,
                                                 float* __restrict__ ii,
                                                 float* __restrict__ coi) {
  __shared__ unsigned cntS[128];
  __shared__ unsigned cntD[128];
  __shared__ unsigned sc2[128];
  __shared__ int eL[3072];
  const int b = blockIdx.x, t = threadIdx.x;
  const int node0 = b << BSHIFT;
  if (t < 128) { cntS[t] = 0u; cntD[t] = 0u; }
  __syncthreads();
  const int sbeg = sbase[b], send = sbase[b + 1];
  for (int j = sbeg + t; j < send; j += 256)
    atomicAdd(&cntS[ebuf2[j]], 1u);
  const int base = bbase[b], end = bbase[b + 1];
  const int cnt = end - base;
  const bool fit = (cnt <= 3072);
  for (int j = t; j < cnt; j += 256) {
    int pk = ebuf[base + j];
    if (fit) eL[j] = pk;
    atomicAdd(&cntD[(unsigned)pk >> 17], 1u);
  }
  __syncthreads();
  unsigned cD = (t < 128) ? cntD[t] : 0u;
  if (t < 128) sc2[t] = cD;
  __syncthreads();
  for (int d = 1; d < 128; d <<= 1) {
    unsigned a = (t < 128 && t >= d) ? sc2[t - d] : 0u;
    __syncthreads();
    if (t < 128) sc2[t] += a;
    __syncthreads();
  }
  if (t < 128) {
    unsigned ex = sc2[t] - cD;
    unsigned cs = cntS[t]; if (cs < 1u) cs = 1u;
    float o = rsqrtf((float)cs);
    int n = node0 + t;
    if (n < N_NODES) {
      oi[n] = o;
      row_ptr[n] = base + (int)ex;
      unsigned c = cD; if (c < 1u) c = 1u;
      float iv = rsqrtf((float)c);
      ii[n] = iv;
      coi[n] = iv * o;
    }
    cntD[t] = ex;
  }
  __syncthreads();
  for (int j = t; j < cnt; j += 256) {
    int pk = fit ? eL[j] : ebuf[base + j];
    unsigned dn = (unsigned)pk >> 17;
    unsigned slot = atomicAdd(&cntD[dn], 1u);
    csr_src[base + (int)slot] = pk & 0x1FFFF;
  }
}

// ---------------- GEMM1 (MFMA bf16): h1b = bf16((x*oi) @ W1), 100k x 128 x 128 ----------------

#define LPAD 136

__global__ __launch_bounds__(256) void k_gemm1(const float* __restrict__ x,
                                               const float* __restrict__ oi,
                                               const unsigned short* __restrict__ Wt1,
                                               unsigned short* __restrict__ h1b) {
  __shared__ unsigned short Xs[64 * LPAD];
  __shared__ unsigned short Ws[128 * LPAD];
  const int t = threadIdx.x;
  const int row0 = blockIdx.x * 64;
#pragma unroll
  for (int j = 0; j < 8; ++j) {
    int q = t + 256 * j;
    int n = q >> 4, c = q & 15;
    *(uint4*)(Ws + n * LPAD + c * 8) = *(const uint4*)(Wt1 + n * 128 + c * 8);
  }
#pragma unroll
  for (int j = 0; j < 4; ++j) {
    int q = t + 256 * j;
    int r = q >> 4, c = q & 15;
    int gr = row0 + r; if (gr >= N_NODES) gr = N_NODES - 1;
    const float* xp = x + (size_t)gr * 128 + c * 8;
    float4 v0 = *(const float4*)(xp);
    float4 v1 = *(const float4*)(xp + 4);
    float s = oi[gr];
    uint4 pk;
    pk.x = pack_bf16x2(v0.x * s, v0.y * s);
    pk.y = pack_bf16x2(v0.z * s, v0.w * s);
    pk.z = pack_bf16x2(v1.x * s, v1.y * s);
    pk.w = pack_bf16x2(v1.z * s, v1.w * s);
    *(uint4*)(Xs + r * LPAD + c * 8) = pk;
  }
  __syncthreads();
  const int w = t >> 6, lane = t & 63;
  const int m = lane & 15;
  const int q8 = (lane >> 4) * 8;
  f32x4 acc[8];
#pragma unroll
  for (int i = 0; i < 8; ++i) acc[i] = (f32x4){0.f, 0.f, 0.f, 0.f};
  const unsigned short* xrow = Xs + (w * 16 + m) * LPAD;
#pragma unroll
  for (int ks = 0; ks < 4; ++ks) {
    bf16x8 a = *(const bf16x8*)(xrow + ks * 32 + q8);
#pragma unroll
    for (int ct = 0; ct < 8; ++ct) {
      bf16x8 b = *(const bf16x8*)(Ws + (ct * 16 + m) * LPAD + ks * 32 + q8);
      acc[ct] = __builtin_amdgcn_mfma_f32_16x16x32_bf16(a, b, acc[ct], 0, 0, 0);
    }
  }
  const int rbase = row0 + w * 16 + (lane >> 4) * 4;
#pragma unroll
  for (int ct = 0; ct < 8; ++ct) {
    int coln = ct * 16 + m;
#pragma unroll
    for (int r = 0; r < 4; ++r) {
      int grow = rbase + r;
      if (grow < N_NODES) h1b[(size_t)grow * 128 + coln] = bf16u(acc[ct][r]);
    }
  }
}

// ---------------- AGG1+GEMM2 fused: h2b = bf16( (coi*relu(sum h1[src])) @ W2 ) -----------

__global__ __launch_bounds__(256) void k_agg1g2(const unsigned short* __restrict__ h1b,
                                                const int* __restrict__ csr_src,
                                                const int* __restrict__ row_ptr,
                                                const float* __restrict__ coi,
                                                const unsigned short* __restrict__ Wt2,
                                                unsigned short* __restrict__ h2b) {
  __shared__ unsigned short Gs[16 * LPAD];
  __shared__ unsigned short Ws[48 * LPAD];
  const int t = threadIdx.x;
  const int node0 = blockIdx.x * 16;
#pragma unroll
  for (int j = 0; j < 3; ++j) {
    int q = t + 256 * j;
    int n = q >> 4, cc = q & 15;
    *(uint4*)(Ws + n * LPAD + cc * 8) = *(const uint4*)(Wt2 + n * 128 + cc * 8);
  }
  const int node = node0 + (t >> 4);
  const int c = t & 15;
  const int beg = row_ptr[node];
  const int end = row_ptr[node + 1];
  float4 a0 = make_float4(0.f, 0.f, 0.f, 0.f);
  float4 a1 = make_float4(0.f, 0.f, 0.f, 0.f);
  int j = beg;
  for (; j + 8 <= end; j += 8) {
    uint4 v[8];
#pragma unroll
    for (int i = 0; i < 8; ++i) {
      int s = csr_src[j + i];
      v[i] = *(const uint4*)(h1b + (size_t)s * 128 + 8 * c);
    }
#pragma unroll
    for (int i = 0; i < 8; ++i) {
      a0.x += bf_lo(v[i].x); a0.y += bf_hi(v[i].x);
      a0.z += bf_lo(v[i].y); a0.w += bf_hi(v[i].y);
      a1.x += bf_lo(v[i].z); a1.y += bf_hi(v[i].z);
      a1.z += bf_lo(v[i].w); a1.w += bf_hi(v[i].w);
    }
  }
  if (j + 4 <= end) {
    uint4 v[4];
#pragma unroll
    for (int i = 0; i < 4; ++i) {
      int s = csr_src[j + i];
      v[i] = *(const uint4*)(h1b + (size_t)s * 128 + 8 * c);
    }
#pragma unroll
    for (int i = 0; i < 4; ++i) {
      a0.x += bf_lo(v[i].x); a0.y += bf_hi(v[i].x);
      a0.z += bf_lo(v[i].y); a0.w += bf_hi(v[i].y);
      a1.x += bf_lo(v[i].z); a1.y += bf_hi(v[i].z);
      a1.z += bf_lo(v[i].w); a1.w += bf_hi(v[i].w);
    }
    j += 4;
  }
  for (; j < end; ++j) {
    int s = csr_src[j];
    uint4 v = *(const uint4*)(h1b + (size_t)s * 128 + 8 * c);
    a0.x += bf_lo(v.x); a0.y += bf_hi(v.x); a0.z += bf_lo(v.y); a0.w += bf_hi(v.y);
    a1.x += bf_lo(v.z); a1.y += bf_hi(v.z); a1.z += bf_lo(v.w); a1.w += bf_hi(v.w);
  }
  float sc = coi[node];
  uint4 pk;
  pk.x = pack_bf16x2(fmaxf(a0.x, 0.f) * sc, fmaxf(a0.y, 0.f) * sc);
  pk.y = pack_bf16x2(fmaxf(a0.z, 0.f) * sc, fmaxf(a0.w, 0.f) * sc);
  pk.z = pack_bf16x2(fmaxf(a1.x, 0.f) * sc, fmaxf(a1.y, 0.f) * sc);
  pk.w = pack_bf16x2(fmaxf(a1.z, 0.f) * sc, fmaxf(a1.w, 0.f) * sc);
  *(uint4*)(Gs + (t >> 4) * LPAD + 8 * c) = pk;
  __syncthreads();
  const int w = t >> 6, lane = t & 63;
  if (w < 3) {
    const int m = lane & 15;
    const int q8 = (lane >> 4) * 8;
    f32x4 acc = (f32x4){0.f, 0.f, 0.f, 0.f};
    const unsigned short* grow_p = Gs + m * LPAD;
#pragma unroll
    for (int ks = 0; ks < 4; ++ks) {
      bf16x8 a = *(const bf16x8*)(grow_p + ks * 32 + q8);
      bf16x8 b = *(const bf16x8*)(Ws + (w * 16 + m) * LPAD + ks * 32 + q8);
      acc = __builtin_amdgcn_mfma_f32_16x16x32_bf16(a, b, acc, 0, 0, 0);
    }
    int coln = w * 16 + m;
    if (coln < 40) {
      const int rbase = (lane >> 4) * 4;
#pragma unroll
      for (int r = 0; r < 4; ++r)
        h2b[(size_t)(node0 + rbase + r) * 64 + coln] = bf16u(acc[r]);
    }
  }
}

// ---------------- AGG2: out = ii * sum h2[src]  (8 lanes/node, uint4; lanes 0-4 active) ----

__global__ __launch_bounds__(256) void k_agg2(const unsigned short* __restrict__ h2b,
                                              const int* __restrict__ csr_src,
                                              const int* __restrict__ row_ptr,
                                              const float* __restrict__ ii,
                                              float* __restrict__ out) {
  const int t = threadIdx.x;
  const int node = blockIdx.x * 32 + (t >> 3);
  const int c = t & 7;
  if (c >= 5) return;  // 40 ch = 5 lanes x 8 ch
  const int beg = row_ptr[node];
  const int end = row_ptr[node + 1];
  float a0 = 0.f, a1 = 0.f, a2 = 0.f, a3 = 0.f, a4 = 0.f, a5 = 0.f, a6 = 0.f, a7 = 0.f;
  int j = beg;
  for (; j + 8 <= end; j += 8) {
    uint4 v[8];
#pragma unroll
    for (int i = 0; i < 8; ++i) {
      int s = csr_src[j + i];
      v[i] = *(const uint4*)(h2b + (size_t)s * 64 + 8 * c);
    }
#pragma unroll
    for (int i = 0; i < 8; ++i) {
      a0 += bf_lo(v[i].x); a1 += bf_hi(v[i].x);
      a2 += bf_lo(v[i].y); a3 += bf_hi(v[i].y);
      a4 += bf_lo(v[i].z); a5 += bf_hi(v[i].z);
      a6 += bf_lo(v[i].w); a7 += bf_hi(v[i].w);
    }
  }
  if (j + 4 <= end) {
    uint4 v[4];
#pragma unroll
    for (int i = 0; i < 4; ++i) {
      int s = csr_src[j + i];
      v[i] = *(const uint4*)(h2b + (size_t)s * 64 + 8 * c);
    }
#pragma unroll
    for (int i = 0; i < 4; ++i) {
      a0 += bf_lo(v[i].x); a1 += bf_hi(v[i].x);
      a2 += bf_lo(v[i].y); a3 += bf_hi(v[i].y);
      a4 += bf_lo(v[i].z); a5 += bf_hi(v[i].z);
      a6 += bf_lo(v[i].w); a7 += bf_hi(v[i].w);
    }
    j += 4;
  }
  for (; j < end; ++j) {
    int s = csr_src[j];
    uint4 v = *(const uint4*)(h2b + (size_t)s * 64 + 8 * c);
    a0 += bf_lo(v.x); a1 += bf_hi(v.x);
    a2 += bf_lo(v.y); a3 += bf_hi(v.y);
    a4 += bf_lo(v.z); a5 += bf_hi(v.z);
    a6 += bf_lo(v.w); a7 += bf_hi(v.w);
  }
  float sc = ii[node];
  float4 o0 = make_float4(a0 * sc, a1 * sc, a2 * sc, a3 * sc);
  float4 o1 = make_float4(a4 * sc, a5 * sc, a6 * sc, a7 * sc);
  float* op = out + (size_t)node * 40 + 8 * c;
  *(float4*)(op) = o0;
  *(float4*)(op + 4) = o1;
}

// ---------------- launch ----------------

extern "C" void kernel_launch(void* const* d_in, const int* in_sizes, int n_in,
                              void* d_out, int out_size, void* d_ws, size_t ws_size,
                              hipStream_t stream) {
  const float* x  = (const float*)d_in[0];
  const int* ei   = (const int*)d_in[1];
  const float* W1 = (const float*)d_in[2];
  const float* W2 = (const float*)d_in[3];
  const int* src = ei;
  const int* dst = ei + N_EDGES;
  float* out = (float*)d_out;

  char* p = (char*)d_ws;
  auto alloc = [&](size_t b) -> void* {
    char* r = p;
    p += (b + 255) & ~(size_t)255;
    return (void*)r;
  };
  float* oi             = (float*)alloc((size_t)N_NODES * 4);
  float* ii             = (float*)alloc((size_t)N_NODES * 4);
  float* coi            = (float*)alloc((size_t)N_NODES * 4);
  int* row_ptr          = (int*)alloc((size_t)(N_NODES + 1) * 4);
  unsigned* histGdT     = (unsigned*)alloc((size_t)NCHUNK * NBUCK * 4);
  unsigned* histGsT     = (unsigned*)alloc((size_t)NCHUNK * NBUCK * 4);
  unsigned* btot        = (unsigned*)alloc((size_t)2 * NBUCK * 4);
  int* bbase            = (int*)alloc((size_t)(NBUCK + 1) * 4);
  int* sbase            = (int*)alloc((size_t)(NBUCK + 1) * 4);
  int* ebuf             = (int*)alloc((size_t)N_EDGES * 4);
  unsigned char* ebuf2  = (unsigned char*)alloc((size_t)N_EDGES);
  int* csr_src          = (int*)alloc((size_t)N_EDGES * 4);
  unsigned short* Wt1   = (unsigned short*)alloc((size_t)128 * 128 * 2);
  unsigned short* Wt2   = (unsigned short*)alloc((size_t)48 * 128 * 2);
  unsigned short* h1b   = (unsigned short*)alloc((size_t)N_NODES * 128 * 2);
  unsigned short* h2b   = (unsigned short*)alloc((size_t)N_NODES * 64 * 2);

  k_hist<<<NCHUNK, 256, 0, stream>>>(src, dst, histGdT, histGsT, W1, W2, Wt1, Wt2);
  k_offs<<<2 * NBG, 256, 0, stream>>>(histGdT, histGsT, btot);
  k_bscan2<<<2, 1024, 0, stream>>>(btot, bbase, sbase, row_ptr);
  k_part<<<NCHUNK, 256, 0, stream>>>(src, dst, histGdT, histGsT, bbase, sbase, ebuf, ebuf2);
  k_buckets<<<NBUCK, 256, 0, stream>>>(ebuf, ebuf2, bbase, sbase, oi, row_ptr, csr_src,
                                       ii, coi);
  k_gemm1<<<(N_NODES + 63) / 64, 256, 0, stream>>>(x, oi, Wt1, h1b);
  k_agg1g2<<<N_NODES / 16, 256, 0, stream>>>(h1b, csr_src, row_ptr, coi, Wt2, h2b);
  k_agg2<<<N_NODES / 32, 256, 0, stream>>>(h2b, csr_src, row_ptr, ii, out);
}

// Round 14
// 249.513 us; speedup vs baseline: 1.0314x; 1.0006x over previous
//
#include <hip/hip_runtime.h>

#define N_NODES 100000
#define N_EDGES 1600000
#define BSHIFT 8
#define NBUCK 391     // ceil(N_NODES/256)
#define NB2 (2 * NBUCK)
#define NCHUNK 500
#define CH 3200       // N_EDGES / NCHUNK exactly
#define NBG 25        // ceil(NBUCK/16) bucket-groups for k_offs
#define ELCAP 4864    // k_buckets LDS edge cache (mean 4092, +12 sigma)

typedef __attribute__((ext_vector_type(8))) short bf16x8;
typedef __attribute__((ext_vector_type(4))) float f32x4;

// bf16 helpers (RTNE pack; unpack = shift to high half)
__device__ __forceinline__ unsigned pack_bf16x2(float a, float b) {
  unsigned ua = __float_as_uint(a);
  unsigned ub = __float_as_uint(b);
  ua = ua + 0x7fffu + ((ua >> 16) & 1u);
  ub = ub + 0x7fffu + ((ub >> 16) & 1u);
  return (ua >> 16) | (ub & 0xffff0000u);
}
__device__ __forceinline__ unsigned short bf16u(float f) {
  unsigned u = __float_as_uint(f);
  u = u + 0x7fffu + ((u >> 16) & 1u);
  return (unsigned short)(u >> 16);
}
__device__ __forceinline__ float bf_lo(unsigned u) { return __uint_as_float(u << 16); }
__device__ __forceinline__ float bf_hi(unsigned u) { return __uint_as_float(u & 0xffff0000u); }

// ---- k_hist: per-chunk histograms -> histG_T[chunk][bucket] (contiguous writes) ---------
// + fused one-time weight prep (blocks 0..63).

__global__ __launch_bounds__(256) void k_hist(const int* __restrict__ src,
                                              const int* __restrict__ dst,
                                              unsigned* __restrict__ histGdT,
                                              unsigned* __restrict__ histGsT,
                                              const float* __restrict__ W1,
                                              const float* __restrict__ W2,
                                              unsigned short* __restrict__ Wt1,
                                              unsigned short* __restrict__ Wt2) {
  __shared__ unsigned hd[NBUCK];
  __shared__ unsigned hs[NBUCK];
  const int t = threadIdx.x, j = blockIdx.x;
  if (j < 64) {  // fused weight prep (once)
    int q = j * 256 + t;
    {
      int n = q >> 7, k = q & 127;
      Wt1[n * 128 + k] = bf16u(W1[k * 128 + n]);
    }
    if (q < 48 * 128) {
      int n = q >> 7, k = q & 127;
      float v = (n < 40) ? W2[k * 40 + n] : 0.f;
      Wt2[n * 128 + k] = bf16u(v);
    }
  }
  for (int i = t; i < NBUCK; i += 256) { hd[i] = 0u; hs[i] = 0u; }
  __syncthreads();
  const int e0 = j * CH;
  for (int e = e0 + t; e < e0 + CH; e += 256) {
    atomicAdd(&hd[(unsigned)dst[e] >> BSHIFT], 1u);
    atomicAdd(&hs[(unsigned)src[e] >> BSHIFT], 1u);
  }
  __syncthreads();
  for (int i = t; i < NBUCK; i += 256) {
    histGdT[(size_t)j * NBUCK + i] = hd[i];
    histGsT[(size_t)j * NBUCK + i] = hs[i];
  }
}

// ---- k_offs: 16 buckets/block, coalesced reads of histG_T; in-place exclusive scan ------

__global__ __launch_bounds__(256) void k_offs(unsigned* __restrict__ histGdT,
                                              unsigned* __restrict__ histGsT,
                                              unsigned* __restrict__ btot) {
  __shared__ unsigned part[16][17];
  __shared__ unsigned base[16][17];
  const int g = blockIdx.x;
  unsigned* H = (g < NBG) ? histGdT : histGsT;
  unsigned* bt = btot + ((g < NBG) ? 0 : NBUCK);
  const int b0 = ((g < NBG) ? g : g - NBG) * 16;
  const int t = threadIdx.x;
  const int js = t >> 4, bl = t & 15;
  const int b = b0 + bl;
  const int j0 = js * 32;
  const int j1 = (j0 + 32 < NCHUNK) ? j0 + 32 : NCHUNK;
  unsigned s = 0;
  if (b < NBUCK)
    for (int j = j0; j < j1; ++j) s += H[(size_t)j * NBUCK + b];
  part[js][bl] = s;
  __syncthreads();
  if (js == 0) {
    unsigned run = 0;
#pragma unroll
    for (int k = 0; k < 16; ++k) { base[k][bl] = run; run += part[k][bl]; }
    if (b < NBUCK) bt[b] = run;
  }
  __syncthreads();
  if (b < NBUCK) {
    unsigned run = base[js][bl];
    for (int j = j0; j < j1; ++j) {
      unsigned v = H[(size_t)j * NBUCK + b];
      H[(size_t)j * NBUCK + b] = run;
      run += v;
    }
  }
}

// two blocks: scan dst totals -> bbase, src totals -> sbase.
__global__ __launch_bounds__(1024) void k_bscan2(const unsigned* __restrict__ btot,
                                                 int* __restrict__ bbase,
                                                 int* __restrict__ sbase,
                                                 int* __restrict__ row_ptr) {
  __shared__ unsigned sd[1024];
  const int t = threadIdx.x;
  const unsigned* bt = btot + (blockIdx.x ? NBUCK : 0);
  int* ob = blockIdx.x ? sbase : bbase;
  unsigned v = (t < NBUCK) ? bt[t] : 0u;
  sd[t] = v;
  __syncthreads();
  for (int d = 1; d < 1024; d <<= 1) {
    unsigned a = (t >= d) ? sd[t - d] : 0u;
    __syncthreads();
    sd[t] += a;
    __syncthreads();
  }
  if (t < NBUCK) ob[t] = (int)(sd[t] - v);
  if (t == 0) {
    ob[NBUCK] = N_EDGES;
    if (blockIdx.x == 0) row_ptr[N_NODES] = N_EDGES;
  }
}

// ---- k_part: LDS counting sort per chunk, both streams, ONE combined scan ---------------

__global__ __launch_bounds__(256) void k_part(const int* __restrict__ src,
                                              const int* __restrict__ dst,
                                              const unsigned* __restrict__ histGdT,
                                              const unsigned* __restrict__ histGsT,
                                              const int* __restrict__ bbase,
                                              const int* __restrict__ sbase,
                                              int* __restrict__ ebuf,
                                              unsigned char* __restrict__ ebuf2) {
  __shared__ int pk_s[CH];
  __shared__ unsigned short bkD[CH];
  __shared__ int srt[CH];
  __shared__ unsigned short bkO[CH];
  __shared__ unsigned cnt[NB2];
  __shared__ int gb[NB2];
  __shared__ unsigned pscan[256];
  const int t = threadIdx.x, j = blockIdx.x;
  const int e0 = j * CH;
  for (int i = t; i < NB2; i += 256) cnt[i] = 0u;
  __syncthreads();
  for (int i = t; i < CH; i += 256) {
    int d = dst[e0 + i], s = src[e0 + i];
    pk_s[i] = ((d & 255) << 17) | s;
    int bd = (unsigned)d >> BSHIFT;
    bkD[i] = (unsigned short)bd;
    atomicAdd(&cnt[bd], 1u);
    atomicAdd(&cnt[NBUCK + ((unsigned)s >> BSHIFT)], 1u);
  }
  __syncthreads();
  unsigned loc[4], ssum = 0;
#pragma unroll
  for (int k = 0; k < 4; ++k) {
    int idx = t * 4 + k;
    loc[k] = (idx < NB2) ? cnt[idx] : 0u;
    ssum += loc[k];
  }
  pscan[t] = ssum;
  __syncthreads();
  for (int d2 = 1; d2 < 256; d2 <<= 1) {
    unsigned a = (t >= d2) ? pscan[t - d2] : 0u;
    __syncthreads();
    pscan[t] += a;
    __syncthreads();
  }
  unsigned run = pscan[t] - ssum;
#pragma unroll
  for (int k = 0; k < 4; ++k) {
    int idx = t * 4 + k;
    if (idx < NBUCK) {
      cnt[idx] = run;
      gb[idx] = bbase[idx] + (int)histGdT[(size_t)j * NBUCK + idx] - (int)run;
    } else if (idx < NB2) {
      unsigned runS = run - CH;
      cnt[idx] = runS;
      int b = idx - NBUCK;
      gb[idx] = sbase[b] + (int)histGsT[(size_t)j * NBUCK + b] - (int)runS;
    }
    run += loc[k];
  }
  __syncthreads();
  for (int i = t; i < CH; i += 256) {
    int b = bkD[i];
    unsigned pos = atomicAdd(&cnt[b], 1u);
    srt[pos] = pk_s[i];
    bkO[pos] = (unsigned short)b;
  }
  __syncthreads();
  for (int i = t; i < CH; i += 256)
    ebuf[gb[bkO[i]] + i] = srt[i];
  __syncthreads();
  unsigned char* srtB = (unsigned char*)srt;
  for (int i = t; i < CH; i += 256) {
    int s = pk_s[i] & 0x1FFFF;
    int b2 = NBUCK + ((unsigned)s >> BSHIFT);
    unsigned pos = atomicAdd(&cnt[b2], 1u);
    srtB[pos] = (unsigned char)(s & 255);
    bkO[pos] = (unsigned short)b2;
  }
  __syncthreads();
  for (int i = t; i < CH; i += 256)
    ebuf2[gb[bkO[i]] + i] = srtB[i];
}

// ---- k_buckets: per-256-node-bucket: degrees -> oi/ii/coi, row_ptr, clustered csr fill --
// ebuf slice cached in LDS (<=ELCAP edges; mean 4092, +12 sigma; global fallback).

__global__ __launch_bounds__(256) void k_buckets(const int* __restrict__ ebuf,
                                                 const unsigned char* __restrict__ ebuf2,
                                                 const int* __restrict__ bbase,
                                                 const int* __restrict__ sbase,
                                                 float* __restrict__ oi,
                                                 int* __restrict__ row_ptr,
                                                 int* __restrict__ csr_src,
                                                 float* __restrict__ ii,
                                                 float* __restrict__ coi) {
  __shared__ unsigned cntS[256];
  __shared__ unsigned cntD[256];
  __shared__ unsigned sc2[256];
  __shared__ int eL[ELCAP];
  const int b = blockIdx.x, t = threadIdx.x;
  const int node0 = b << BSHIFT;
  cntS[t] = 0u; cntD[t] = 0u;
  __syncthreads();
  const int sbeg = sbase[b], send = sbase[b + 1];
  for (int j = sbeg + t; j < send; j += 256)
    atomicAdd(&cntS[ebuf2[j]], 1u);
  const int base = bbase[b], end = bbase[b + 1];
  const int cnt = end - base;
  const bool fit = (cnt <= ELCAP);
  for (int j = t; j < cnt; j += 256) {
    int pk = ebuf[base + j];
    if (fit) eL[j] = pk;
    atomicAdd(&cntD[(unsigned)pk >> 17], 1u);
  }
  __syncthreads();
  unsigned cD = cntD[t];
  sc2[t] = cD;
  __syncthreads();
  for (int d = 1; d < 256; d <<= 1) {
    unsigned a = (t >= d) ? sc2[t - d] : 0u;
    __syncthreads();
    sc2[t] += a;
    __syncthreads();
  }
  {
    unsigned ex = sc2[t] - cD;  // exclusive prefix
    unsigned cs = cntS[t]; if (cs < 1u) cs = 1u;
    float o = rsqrtf((float)cs);
    int n = node0 + t;
    if (n < N_NODES) {
      oi[n] = o;
      row_ptr[n] = base + (int)ex;
      unsigned c = cD; if (c < 1u) c = 1u;
      float iv = rsqrtf((float)c);
      ii[n] = iv;
      coi[n] = iv * o;  // relu(ii*agg)*oi == (ii*oi)*relu(agg)
    }
    cntD[t] = ex;  // reuse as cursors
  }
  __syncthreads();
  for (int j = t; j < cnt; j += 256) {
    int pk = fit ? eL[j] : ebuf[base + j];
    unsigned dn = (unsigned)pk >> 17;
    unsigned slot = atomicAdd(&cntD[dn], 1u);
    csr_src[base + (int)slot] = pk & 0x1FFFF;
  }
}

// ---------------- GEMM1 (MFMA bf16): h1b = bf16((x*oi) @ W1), 100k x 128 x 128 ----------------

#define LPAD 136

__global__ __launch_bounds__(256) void k_gemm1(const float* __restrict__ x,
                                               const float* __restrict__ oi,
                                               const unsigned short* __restrict__ Wt1,
                                               unsigned short* __restrict__ h1b) {
  __shared__ unsigned short Xs[64 * LPAD];
  __shared__ unsigned short Ws[128 * LPAD];
  const int t = threadIdx.x;
  const int row0 = blockIdx.x * 64;
#pragma unroll
  for (int j = 0; j < 8; ++j) {
    int q = t + 256 * j;
    int n = q >> 4, c = q & 15;
    *(uint4*)(Ws + n * LPAD + c * 8) = *(const uint4*)(Wt1 + n * 128 + c * 8);
  }
#pragma unroll
  for (int j = 0; j < 4; ++j) {
    int q = t + 256 * j;
    int r = q >> 4, c = q & 15;
    int gr = row0 + r; if (gr >= N_NODES) gr = N_NODES - 1;
    const float* xp = x + (size_t)gr * 128 + c * 8;
    float4 v0 = *(const float4*)(xp);
    float4 v1 = *(const float4*)(xp + 4);
    float s = oi[gr];
    uint4 pk;
    pk.x = pack_bf16x2(v0.x * s, v0.y * s);
    pk.y = pack_bf16x2(v0.z * s, v0.w * s);
    pk.z = pack_bf16x2(v1.x * s, v1.y * s);
    pk.w = pack_bf16x2(v1.z * s, v1.w * s);
    *(uint4*)(Xs + r * LPAD + c * 8) = pk;
  }
  __syncthreads();
  const int w = t >> 6, lane = t & 63;
  const int m = lane & 15;
  const int q8 = (lane >> 4) * 8;
  f32x4 acc[8];
#pragma unroll
  for (int i = 0; i < 8; ++i) acc[i] = (f32x4){0.f, 0.f, 0.f, 0.f};
  const unsigned short* xrow = Xs + (w * 16 + m) * LPAD;
#pragma unroll
  for (int ks = 0; ks < 4; ++ks) {
    bf16x8 a = *(const bf16x8*)(xrow + ks * 32 + q8);
#pragma unroll
    for (int ct = 0; ct < 8; ++ct) {
      bf16x8 b = *(const bf16x8*)(Ws + (ct * 16 + m) * LPAD + ks * 32 + q8);
      acc[ct] = __builtin_amdgcn_mfma_f32_16x16x32_bf16(a, b, acc[ct], 0, 0, 0);
    }
  }
  const int rbase = row0 + w * 16 + (lane >> 4) * 4;
#pragma unroll
  for (int ct = 0; ct < 8; ++ct) {
    int coln = ct * 16 + m;
#pragma unroll
    for (int r = 0; r < 4; ++r) {
      int grow = rbase + r;
      if (grow < N_NODES) h1b[(size_t)grow * 128 + coln] = bf16u(acc[ct][r]);
    }
  }
}

// ---------------- AGG1+GEMM2 fused: h2b = bf16( (coi*relu(sum h1[src])) @ W2 ) -----------

__global__ __launch_bounds__(256) void k_agg1g2(const unsigned short* __restrict__ h1b,
                                                const int* __restrict__ csr_src,
                                                const int* __restrict__ row_ptr,
                                                const float* __restrict__ coi,
                                                const unsigned short* __restrict__ Wt2,
                                                unsigned short* __restrict__ h2b) {
  __shared__ unsigned short Gs[16 * LPAD];
  __shared__ unsigned short Ws[48 * LPAD];
  const int t = threadIdx.x;
  const int node0 = blockIdx.x * 16;
#pragma unroll
  for (int j = 0; j < 3; ++j) {
    int q = t + 256 * j;
    int n = q >> 4, cc = q & 15;
    *(uint4*)(Ws + n * LPAD + cc * 8) = *(const uint4*)(Wt2 + n * 128 + cc * 8);
  }
  const int node = node0 + (t >> 4);
  const int c = t & 15;
  const int beg = row_ptr[node];
  const int end = row_ptr[node + 1];
  float4 a0 = make_float4(0.f, 0.f, 0.f, 0.f);
  float4 a1 = make_float4(0.f, 0.f, 0.f, 0.f);
  int j = beg;
  for (; j + 8 <= end; j += 8) {
    uint4 v[8];
#pragma unroll
    for (int i = 0; i < 8; ++i) {
      int s = csr_src[j + i];
      v[i] = *(const uint4*)(h1b + (size_t)s * 128 + 8 * c);
    }
#pragma unroll
    for (int i = 0; i < 8; ++i) {
      a0.x += bf_lo(v[i].x); a0.y += bf_hi(v[i].x);
      a0.z += bf_lo(v[i].y); a0.w += bf_hi(v[i].y);
      a1.x += bf_lo(v[i].z); a1.y += bf_hi(v[i].z);
      a1.z += bf_lo(v[i].w); a1.w += bf_hi(v[i].w);
    }
  }
  if (j + 4 <= end) {
    uint4 v[4];
#pragma unroll
    for (int i = 0; i < 4; ++i) {
      int s = csr_src[j + i];
      v[i] = *(const uint4*)(h1b + (size_t)s * 128 + 8 * c);
    }
#pragma unroll
    for (int i = 0; i < 4; ++i) {
      a0.x += bf_lo(v[i].x); a0.y += bf_hi(v[i].x);
      a0.z += bf_lo(v[i].y); a0.w += bf_hi(v[i].y);
      a1.x += bf_lo(v[i].z); a1.y += bf_hi(v[i].z);
      a1.z += bf_lo(v[i].w); a1.w += bf_hi(v[i].w);
    }
    j += 4;
  }
  for (; j < end; ++j) {
    int s = csr_src[j];
    uint4 v = *(const uint4*)(h1b + (size_t)s * 128 + 8 * c);
    a0.x += bf_lo(v.x); a0.y += bf_hi(v.x); a0.z += bf_lo(v.y); a0.w += bf_hi(v.y);
    a1.x += bf_lo(v.z); a1.y += bf_hi(v.z); a1.z += bf_lo(v.w); a1.w += bf_hi(v.w);
  }
  float sc = coi[node];
  uint4 pk;
  pk.x = pack_bf16x2(fmaxf(a0.x, 0.f) * sc, fmaxf(a0.y, 0.f) * sc);
  pk.y = pack_bf16x2(fmaxf(a0.z, 0.f) * sc, fmaxf(a0.w, 0.f) * sc);
  pk.z = pack_bf16x2(fmaxf(a1.x, 0.f) * sc, fmaxf(a1.y, 0.f) * sc);
  pk.w = pack_bf16x2(fmaxf(a1.z, 0.f) * sc, fmaxf(a1.w, 0.f) * sc);
  *(uint4*)(Gs + (t >> 4) * LPAD + 8 * c) = pk;
  __syncthreads();
  const int w = t >> 6, lane = t & 63;
  if (w < 3) {
    const int m = lane & 15;
    const int q8 = (lane >> 4) * 8;
    f32x4 acc = (f32x4){0.f, 0.f, 0.f, 0.f};
    const unsigned short* grow_p = Gs + m * LPAD;
#pragma unroll
    for (int ks = 0; ks < 4; ++ks) {
      bf16x8 a = *(const bf16x8*)(grow_p + ks * 32 + q8);
      bf16x8 b = *(const bf16x8*)(Ws + (w * 16 + m) * LPAD + ks * 32 + q8);
      acc = __builtin_amdgcn_mfma_f32_16x16x32_bf16(a, b, acc, 0, 0, 0);
    }
    int coln = w * 16 + m;
    if (coln < 40) {
      const int rbase = (lane >> 4) * 4;
#pragma unroll
      for (int r = 0; r < 4; ++r)
        h2b[(size_t)(node0 + rbase + r) * 64 + coln] = bf16u(acc[r]);
    }
  }
}

// ---------------- AGG2: out = ii * sum h2[src]  (8 lanes/node, uint4; lanes 0-4 active) ----

__global__ __launch_bounds__(256) void k_agg2(const unsigned short* __restrict__ h2b,
                                              const int* __restrict__ csr_src,
                                              const int* __restrict__ row_ptr,
                                              const float* __restrict__ ii,
                                              float* __restrict__ out) {
  const int t = threadIdx.x;
  const int node = blockIdx.x * 32 + (t >> 3);
  const int c = t & 7;
  if (c >= 5) return;  // 40 ch = 5 lanes x 8 ch
  const int beg = row_ptr[node];
  const int end = row_ptr[node + 1];
  float a0 = 0.f, a1 = 0.f, a2 = 0.f, a3 = 0.f, a4 = 0.f, a5 = 0.f, a6 = 0.f, a7 = 0.f;
  int j = beg;
  for (; j + 8 <= end; j += 8) {
    uint4 v[8];
#pragma unroll
    for (int i = 0; i < 8; ++i) {
      int s = csr_src[j + i];
      v[i] = *(const uint4*)(h2b + (size_t)s * 64 + 8 * c);
    }
#pragma unroll
    for (int i = 0; i < 8; ++i) {
      a0 += bf_lo(v[i].x); a1 += bf_hi(v[i].x);
      a2 += bf_lo(v[i].y); a3 += bf_hi(v[i].y);
      a4 += bf_lo(v[i].z); a5 += bf_hi(v[i].z);
      a6 += bf_lo(v[i].w); a7 += bf_hi(v[i].w);
    }
  }
  if (j + 4 <= end) {
    uint4 v[4];
#pragma unroll
    for (int i = 0; i < 4; ++i) {
      int s = csr_src[j + i];
      v[i] = *(const uint4*)(h2b + (size_t)s * 64 + 8 * c);
    }
#pragma unroll
    for (int i = 0; i < 4; ++i) {
      a0 += bf_lo(v[i].x); a1 += bf_hi(v[i].x);
      a2 += bf_lo(v[i].y); a3 += bf_hi(v[i].y);
      a4 += bf_lo(v[i].z); a5 += bf_hi(v[i].z);
      a6 += bf_lo(v[i].w); a7 += bf_hi(v[i].w);
    }
    j += 4;
  }
  for (; j < end; ++j) {
    int s = csr_src[j];
    uint4 v = *(const uint4*)(h2b + (size_t)s * 64 + 8 * c);
    a0 += bf_lo(v.x); a1 += bf_hi(v.x);
    a2 += bf_lo(v.y); a3 += bf_hi(v.y);
    a4 += bf_lo(v.z); a5 += bf_hi(v.z);
    a6 += bf_lo(v.w); a7 += bf_hi(v.w);
  }
  float sc = ii[node];
  float4 o0 = make_float4(a0 * sc, a1 * sc, a2 * sc, a3 * sc);
  float4 o1 = make_float4(a4 * sc, a5 * sc, a6 * sc, a7 * sc);
  float* op = out + (size_t)node * 40 + 8 * c;
  *(float4*)(op) = o0;
  *(float4*)(op + 4) = o1;
}

// ---------------- launch ----------------

extern "C" void kernel_launch(void* const* d_in, const int* in_sizes, int n_in,
                              void* d_out, int out_size, void* d_ws, size_t ws_size,
                              hipStream_t stream) {
  const float* x  = (const float*)d_in[0];
  const int* ei   = (const int*)d_in[1];
  const float* W1 = (const float*)d_in[2];
  const float* W2 = (const float*)d_in[3];
  const int* src = ei;
  const int* dst = ei + N_EDGES;
  float* out = (float*)d_out;

  char* p = (char*)d_ws;
  auto alloc = [&](size_t b) -> void* {
    char* r = p;
    p += (b + 255) & ~(size_t)255;
    return (void*)r;
  };
  float* oi             = (float*)alloc((size_t)N_NODES * 4);
  float* ii             = (float*)alloc((size_t)N_NODES * 4);
  float* coi            = (float*)alloc((size_t)N_NODES * 4);
  int* row_ptr          = (int*)alloc((size_t)(N_NODES + 1) * 4);
  unsigned* histGdT     = (unsigned*)alloc((size_t)NCHUNK * NBUCK * 4);
  unsigned* histGsT     = (unsigned*)alloc((size_t)NCHUNK * NBUCK * 4);
  unsigned* btot        = (unsigned*)alloc((size_t)2 * NBUCK * 4);
  int* bbase            = (int*)alloc((size_t)(NBUCK + 1) * 4);
  int* sbase            = (int*)alloc((size_t)(NBUCK + 1) * 4);
  int* ebuf             = (int*)alloc((size_t)N_EDGES * 4);
  unsigned char* ebuf2  = (unsigned char*)alloc((size_t)N_EDGES);
  int* csr_src          = (int*)alloc((size_t)N_EDGES * 4);
  unsigned short* Wt1   = (unsigned short*)alloc((size_t)128 * 128 * 2);
  unsigned short* Wt2   = (unsigned short*)alloc((size_t)48 * 128 * 2);
  unsigned short* h1b   = (unsigned short*)alloc((size_t)N_NODES * 128 * 2);
  unsigned short* h2b   = (unsigned short*)alloc((size_t)N_NODES * 64 * 2);

  k_hist<<<NCHUNK, 256, 0, stream>>>(src, dst, histGdT, histGsT, W1, W2, Wt1, Wt2);
  k_offs<<<2 * NBG, 256, 0, stream>>>(histGdT, histGsT, btot);
  k_bscan2<<<2, 1024, 0, stream>>>(btot, bbase, sbase, row_ptr);
  k_part<<<NCHUNK, 256, 0, stream>>>(src, dst, histGdT, histGsT, bbase, sbase, ebuf, ebuf2);
  k_buckets<<<NBUCK, 256, 0, stream>>>(ebuf, ebuf2, bbase, sbase, oi, row_ptr, csr_src,
                                       ii, coi);
  k_gemm1<<<(N_NODES + 63) / 64, 256, 0, stream>>>(x, oi, Wt1, h1b);
  k_agg1g2<<<N_NODES / 16, 256, 0, stream>>>(h1b, csr_src, row_ptr, coi, Wt2, h2b);
  k_agg2<<<N_NODES / 32, 256, 0, stream>>>(h2b, csr_src, row_ptr, ii, out);
}